// Round 2
// baseline (6771.851 us; speedup 1.0000x reference)
//
#include <hip/hip_runtime.h>
#include <math.h>

// Problem constants (match reference)
#define NN 50000
#define SEQ 52
#define FIN 16
#define HD 128
#define NEG_SLOPE 0.2f

typedef short bf16x8 __attribute__((ext_vector_type(8)));   // 8 bf16 (4 VGPRs)
typedef float f32x16 __attribute__((ext_vector_type(16)));  // 32x32 MFMA C/D

__device__ __forceinline__ short f2bf(float x) {
    unsigned u = __float_as_uint(x);
    u += 0x7fffu + ((u >> 16) & 1u);   // round-to-nearest-even
    return (short)(u >> 16);
}
__device__ __forceinline__ float b2f(short s) {
    return __uint_as_float(((unsigned)(unsigned short)s) << 16);
}

// ---------------------------------------------------------------------------
// CSR build kernels (run once per launch; graph is static across timesteps)
// ---------------------------------------------------------------------------
__global__ void deg_init_kernel(int* deg, int n) {
    int i = blockIdx.x * blockDim.x + threadIdx.x;
    if (i < n) deg[i] = 1;  // self-loop
}

__global__ void deg_count_kernel(const int* __restrict__ dst, int* deg, int e) {
    int i = blockIdx.x * blockDim.x + threadIdx.x;
    if (i < e) atomicAdd(&deg[dst[i]], 1);
}

__global__ __launch_bounds__(1024) void scan_kernel(const int* __restrict__ deg,
                                                    int* row_ptr, int n) {
    __shared__ int buf[1024];
    __shared__ int carry;
    int tid = threadIdx.x;
    if (tid == 0) carry = 0;
    __syncthreads();
    for (int base = 0; base < n; base += 1024) {
        int i = base + tid;
        int v = (i < n) ? deg[i] : 0;
        buf[tid] = v;
        __syncthreads();
        for (int off = 1; off < 1024; off <<= 1) {
            int t = (tid >= off) ? buf[tid - off] : 0;
            __syncthreads();
            buf[tid] += t;
            __syncthreads();
        }
        if (i < n) row_ptr[i] = carry + buf[tid] - v;  // exclusive
        __syncthreads();
        if (tid == 1023) carry += buf[1023];
        __syncthreads();
    }
    if (tid == 0) row_ptr[n] = carry;
}

__global__ void selfloop_kernel(const int* __restrict__ row_ptr, int* cursor,
                                int* col, int n) {
    int i = blockIdx.x * blockDim.x + threadIdx.x;
    if (i < n) {
        int p = row_ptr[i];
        col[p] = i;          // self-loop first
        cursor[i] = p + 1;
    }
}

__global__ void scatter_kernel(const int* __restrict__ src, const int* __restrict__ dst,
                               int* cursor, int* col, int e) {
    int i = blockIdx.x * blockDim.x + threadIdx.x;
    if (i < e) {
        int p = atomicAdd(&cursor[dst[i]], 1);
        col[p] = src[i];
    }
}

// ---------------------------------------------------------------------------
// Pack W_ih/W_hh into MFMA B-fragment order, split bf16 hi/lo.
// Index: ((((g*4+slab)*8+ks)*4+which)*64+lane)*8 shorts,
//   which: 0=ih_hi 1=ih_lo 2=hh_hi 3=hh_lo
//   col = slab*32 + (lane&31), kcol = ks*16 + (lane>>5)*8
// ---------------------------------------------------------------------------
__global__ void wpack_kernel(const float* __restrict__ Wi, const float* __restrict__ Wh,
                             short* __restrict__ wfrag) {
    int idx = blockIdx.x * blockDim.x + threadIdx.x;
    if (idx >= 3 * 4 * 8 * 4 * 64) return;
    int lane = idx & 63;
    int which = (idx >> 6) & 3;
    int ks = (idx >> 8) & 7;
    int slab = (idx >> 11) & 3;
    int g = idx >> 13;
    int col = slab * 32 + (lane & 31);
    int kcol = ks * 16 + (lane >> 5) * 8;
    const float* Wsrc = (which < 2) ? Wi : Wh;
    const float* row = Wsrc + (size_t)(g * HD + col) * HD + kcol;
    short* dstp = wfrag + (size_t)idx * 8;
    bool lo = (which & 1);
#pragma unroll
    for (int e = 0; e < 8; ++e) {
        float v = row[e];
        short hi = f2bf(v);
        dstp[e] = lo ? f2bf(v - b2f(hi)) : hi;
    }
}

// ---------------------------------------------------------------------------
// Per-timestep kernels
// ---------------------------------------------------------------------------

// xp = x_t @ Wg (stored bf16); a_s = xp.att_src ; a_d = xp.att_dst
__global__ __launch_bounds__(256) void xp_kernel(
    const float* __restrict__ x, const float* __restrict__ Wg,
    const float* __restrict__ att_src, const float* __restrict__ att_dst,
    unsigned* __restrict__ xpb, float* __restrict__ a_s, float* __restrict__ a_d, int n) {
    int wave = (blockIdx.x * blockDim.x + threadIdx.x) >> 6;
    int lane = threadIdx.x & 63;
    if (wave >= n) return;
    const float* xr = x + (size_t)wave * FIN;
    float xv[FIN];
#pragma unroll
    for (int k = 0; k < FIN; ++k) xv[k] = xr[k];
    int c0 = 2 * lane, c1 = 2 * lane + 1;
    float v0 = 0.f, v1 = 0.f;
#pragma unroll
    for (int k = 0; k < FIN; ++k) {
        v0 += xv[k] * Wg[k * HD + c0];
        v1 += xv[k] * Wg[k * HD + c1];
    }
    unsigned p = (unsigned)(unsigned short)f2bf(v0) |
                 ((unsigned)(unsigned short)f2bf(v1) << 16);
    xpb[(size_t)wave * 64 + lane] = p;
    float s = v0 * att_src[c0] + v1 * att_src[c1];
    float d = v0 * att_dst[c0] + v1 * att_dst[c1];
#pragma unroll
    for (int off = 32; off; off >>= 1) {
        s += __shfl_xor(s, off);
        d += __shfl_xor(d, off);
    }
    if (lane == 0) { a_s[wave] = s; a_d[wave] = d; }
}

// GAT softmax-aggregate: one wave per dst node, bf16 xp rows (256B/edge).
// Phase 1: lane e handles edge e of a <=64-edge chunk (parallel gathers).
// Phase 2: 4 edge-groups x 16 feature-lanes; (src,wgt) via exec-uniform
//   __shfl; rows streamed 4-deep (R2: was 2-deep) so each eg keeps up to
//   4 independent 16B loads in flight.
__global__ __launch_bounds__(256) void gat_kernel(
    const int* __restrict__ row_ptr, const int* __restrict__ col,
    const float* __restrict__ a_s, const float* __restrict__ a_d,
    const short* __restrict__ xpb, const float* __restrict__ bias_g,
    float* __restrict__ spatial, int n) {
    int wave = (blockIdx.x * blockDim.x + threadIdx.x) >> 6;
    int lane = threadIdx.x & 63;
    if (wave >= n) return;
    int start = row_ptr[wave], end = row_ptr[wave + 1];
    int eg = lane >> 4;   // edge group 0..3
    int fg = lane & 15;   // feature lane 0..15 (features fg*8..fg*8+7)
    float ad = a_d[wave];
    float acc[8] = {0.f, 0.f, 0.f, 0.f, 0.f, 0.f, 0.f, 0.f};
    float dpart = 0.f;    // per-lane partial denom

    for (int base = start; base < end; base += 64) {
        int cnt = end - base;
        if (cnt > 64) cnt = 64;

        // ---- phase 1: one lane per edge, fully parallel gathers ----
        int s = 0;
        float wgt = 0.f;
        if (lane < cnt) {
            s = col[base + lane];
            float e = a_s[s] + ad;
            e = (e > 0.f) ? e : NEG_SLOPE * e;
            wgt = __expf(e);
        }
        dpart += wgt;

        // ---- phase 2: stream rows, 4 loads in flight per edge group ----
        int nk = (cnt + 3) >> 2;  // wave-uniform
        int k = 0;
        for (; k + 4 <= nk; k += 4) {
            int si[4];
            float wt[4];
#pragma unroll
            for (int u = 0; u < 4; ++u) {
                int e0 = eg + 4 * (k + u);
                int c0 = (e0 < cnt) ? e0 : 0;
                si[u] = __shfl(s, c0);
                wt[u] = __shfl(wgt, c0);
                if (e0 >= cnt) wt[u] = 0.f;
            }
            bf16x8 r[4];
#pragma unroll
            for (int u = 0; u < 4; ++u)
                r[u] = *(const bf16x8*)(xpb + (size_t)si[u] * HD + fg * 8);
#pragma unroll
            for (int u = 0; u < 4; ++u)
#pragma unroll
                for (int j = 0; j < 8; ++j) acc[j] += wt[u] * b2f(r[u][j]);
        }
        for (; k < nk; ++k) {
            int e0 = eg + 4 * k;
            int c0 = (e0 < cnt) ? e0 : 0;
            int si0 = __shfl(s, c0);
            float w0 = __shfl(wgt, c0);
            if (e0 >= cnt) w0 = 0.f;
            bf16x8 r0 = *(const bf16x8*)(xpb + (size_t)si0 * HD + fg * 8);
#pragma unroll
            for (int j = 0; j < 8; ++j) acc[j] += w0 * b2f(r0[j]);
        }
    }

    // denom: full 64-lane reduce (each lane held distinct edges)
#pragma unroll
    for (int off = 32; off; off >>= 1) dpart += __shfl_xor(dpart, off);
    // acc: reduce across the 4 edge groups (lane bits 4,5)
#pragma unroll
    for (int j = 0; j < 8; ++j) {
        acc[j] += __shfl_xor(acc[j], 16);
        acc[j] += __shfl_xor(acc[j], 32);
    }
    float inv = __fdividef(1.f, dpart);
    // each lane writes 2 of its 8 features: f = fg*8 + eg*2 + jj
#pragma unroll
    for (int jj = 0; jj < 2; ++jj) {
        int f = fg * 8 + eg * 2 + jj;
        float o = acc[eg * 2 + jj] * inv + bias_g[f];
        spatial[(size_t)wave * HD + f] = fmaxf(o, 0.f);
    }
}

// ---------------------------------------------------------------------------
// MFMA GRU (R2): 64-node tile per block, 4 waves; each wave computes its
// 32-col output slab for TWO 32-node M-tiles with the SAME weight fragments.
//   -> weight traffic through L1/L2 halves: 614 -> 307 MB/step
//   (1563 blocks x 393KB -> 782 x 393KB).
// Registers: acc 2x(2+1+1) f32x16 = 128, weights single-buffered 12 bf16x8
// = 48, frags/misc ~60 -> ~240 <= 256 at (256,2). The single-buffer L2
// stall per ks (~250cy) is covered by 2 waves/SIMD + 8 independent
// accumulator chains. LDS = 64KB (2 blocks/CU).
// Tail: fast tanh via __expf (libm tanhf was ~50+cy x 16 calls/lane).
// ---------------------------------------------------------------------------
__global__ __launch_bounds__(256, 2) void gru_mfma_kernel(
    const float* __restrict__ spatial, float* __restrict__ h,
    const short* __restrict__ wfrag,
    const float* __restrict__ b_ih, const float* __restrict__ b_hh, int n) {
    __shared__ bf16x8 sSH[2][512];  // spatial hi  [tile][ks*64+lane]
    __shared__ bf16x8 sSL[2][512];  // spatial lo
    __shared__ bf16x8 sHH[2][512];  // h hi
    __shared__ bf16x8 sHL[2][512];  // h lo

    int t = threadIdx.x;
    int lane = t & 63;
    int w = t >> 6;
    int n0 = blockIdx.x * 64;

    // ---- stage: wave w converts k-steps 2w,2w+1 for both 32-row tiles ----
#pragma unroll
    for (int q = 0; q < 4; ++q) {
        int tile = q >> 1;
        int ks = w * 2 + (q & 1);
        int row = n0 + tile * 32 + (lane & 31);
        if (row >= n) row = n - 1;
        int kcol = ks * 16 + (lane >> 5) * 8;
        const float* sp = spatial + (size_t)row * HD + kcol;
        const float* hp = h + (size_t)row * HD + kcol;
        float s8[8], h8[8];
        *(float4*)(s8) = *(const float4*)(sp);
        *(float4*)(s8 + 4) = *(const float4*)(sp + 4);
        *(float4*)(h8) = *(const float4*)(hp);
        *(float4*)(h8 + 4) = *(const float4*)(hp + 4);
        bf16x8 sh, sl, hh, hl;
#pragma unroll
        for (int j = 0; j < 8; ++j) {
            short a = f2bf(s8[j]);
            sh[j] = a;
            sl[j] = f2bf(s8[j] - b2f(a));
            short b = f2bf(h8[j]);
            hh[j] = b;
            hl[j] = f2bf(h8[j] - b2f(b));
        }
        int li = ks * 64 + lane;
        sSH[tile][li] = sh; sSL[tile][li] = sl;
        sHH[tile][li] = hh; sHL[tile][li] = hl;
    }
    __syncthreads();

    int j0 = w * 32;
    int cj = lane & 31;       // column within wave's 32-col slab
    int kh = lane >> 5;       // k-half for frags

    f32x16 arz[2][2], ain[2], ahn[2];  // [tile][...]: 8 accs = 128 VGPR
#pragma unroll
    for (int tile = 0; tile < 2; ++tile)
#pragma unroll
        for (int r = 0; r < 16; ++r) {
            arz[tile][0][r] = 0.f; arz[tile][1][r] = 0.f;
            ain[tile][r] = 0.f; ahn[tile][r] = 0.f;
        }

    // fragment-ordered weight base for this wave: + g*65536 + ks*2048 + which*512
    const short* wb = wfrag + (size_t)w * 16384 + (size_t)lane * 8;

#pragma unroll
    for (int ks = 0; ks < 8; ++ks) {
        // single-buffered weight fragments for this k-step (reused by 2 tiles)
        bf16x8 wv[12];
#pragma unroll
        for (int g = 0; g < 3; ++g)
#pragma unroll
            for (int q = 0; q < 4; ++q)
                wv[g * 4 + q] = *(const bf16x8*)(wb + g * 65536 + ks * 2048 + q * 512);

        int li = ks * 64 + lane;
#pragma unroll
        for (int tile = 0; tile < 2; ++tile) {
            bf16x8 aSH = sSH[tile][li];
            bf16x8 aSL = sSL[tile][li];
            bf16x8 aHH = sHH[tile][li];
            bf16x8 aHL = sHL[tile][li];
            // r and z gates: both GEMMs into one accumulator
#pragma unroll
            for (int g = 0; g < 2; ++g) {
                bf16x8 wih = wv[g * 4 + 0];
                bf16x8 wil = wv[g * 4 + 1];
                bf16x8 whh = wv[g * 4 + 2];
                bf16x8 whl = wv[g * 4 + 3];
                arz[tile][g] = __builtin_amdgcn_mfma_f32_32x32x16_bf16(aSH, wih, arz[tile][g], 0, 0, 0);
                arz[tile][g] = __builtin_amdgcn_mfma_f32_32x32x16_bf16(aHH, whh, arz[tile][g], 0, 0, 0);
                arz[tile][g] = __builtin_amdgcn_mfma_f32_32x32x16_bf16(aSL, wih, arz[tile][g], 0, 0, 0);
                arz[tile][g] = __builtin_amdgcn_mfma_f32_32x32x16_bf16(aHL, whh, arz[tile][g], 0, 0, 0);
                arz[tile][g] = __builtin_amdgcn_mfma_f32_32x32x16_bf16(aSH, wil, arz[tile][g], 0, 0, 0);
                arz[tile][g] = __builtin_amdgcn_mfma_f32_32x32x16_bf16(aHH, whl, arz[tile][g], 0, 0, 0);
            }
            // n gate: separate accs (r multiplies h_n before tanh)
            {
                bf16x8 wih = wv[8];
                bf16x8 wil = wv[9];
                bf16x8 whh = wv[10];
                bf16x8 whl = wv[11];
                ain[tile] = __builtin_amdgcn_mfma_f32_32x32x16_bf16(aSH, wih, ain[tile], 0, 0, 0);
                ahn[tile] = __builtin_amdgcn_mfma_f32_32x32x16_bf16(aHH, whh, ahn[tile], 0, 0, 0);
                ain[tile] = __builtin_amdgcn_mfma_f32_32x32x16_bf16(aSL, wih, ain[tile], 0, 0, 0);
                ahn[tile] = __builtin_amdgcn_mfma_f32_32x32x16_bf16(aHL, whh, ahn[tile], 0, 0, 0);
                ain[tile] = __builtin_amdgcn_mfma_f32_32x32x16_bf16(aSH, wil, ain[tile], 0, 0, 0);
                ahn[tile] = __builtin_amdgcn_mfma_f32_32x32x16_bf16(aHH, whl, ahn[tile], 0, 0, 0);
            }
        }
    }

    // ---- wave-local GRU elementwise + h write ----
    int j = j0 + cj;
    float brz0 = b_ih[j] + b_hh[j];
    float brz1 = b_ih[HD + j] + b_hh[HD + j];
    float bin_ = b_ih[2 * HD + j];
    float bhn = b_hh[2 * HD + j];
    int ksj = j >> 4, halfj = (j >> 3) & 1, ej = j & 7;

#pragma unroll
    for (int tile = 0; tile < 2; ++tile) {
        const short* hhs = (const short*)&sHH[tile][0];
        const short* hls = (const short*)&sHL[tile][0];
#pragma unroll
        for (int r = 0; r < 16; ++r) {
            int nl = (r & 3) + 8 * (r >> 2) + 4 * kh;  // C/D row mapping (m74/m101)
            int node = n0 + tile * 32 + nl;
            if (node < n) {
                float rr = __fdividef(1.f, 1.f + __expf(-(arz[tile][0][r] + brz0)));
                float zz = __fdividef(1.f, 1.f + __expf(-(arz[tile][1][r] + brz1)));
                float u = ain[tile][r] + bin_ + rr * (ahn[tile][r] + bhn);
                float ex = __expf(2.f * u);
                float nn2 = 1.f - __fdividef(2.f, ex + 1.f);  // tanh(u)
                int li = (ksj * 64 + nl + 32 * halfj) * 8 + ej;
                float hold = b2f(hhs[li]) + b2f(hls[li]);
                h[(size_t)node * HD + j] = (1.f - zz) * nn2 + zz * hold;
            }
        }
    }
}

// out[n] = h[n] . W_fc + b_fc   (one wave per node)
__global__ __launch_bounds__(256) void fc_kernel(
    const float* __restrict__ h, const float* __restrict__ W_fc,
    const float* __restrict__ b_fc, float* __restrict__ out, int n) {
    int wave = (blockIdx.x * blockDim.x + threadIdx.x) >> 6;
    int lane = threadIdx.x & 63;
    if (wave >= n) return;
    float v = h[(size_t)wave * HD + lane] * W_fc[lane] +
              h[(size_t)wave * HD + lane + 64] * W_fc[lane + 64];
#pragma unroll
    for (int off = 32; off; off >>= 1) v += __shfl_xor(v, off);
    if (lane == 0) out[wave] = v + b_fc[0];
}

// ---------------------------------------------------------------------------
extern "C" void kernel_launch(void* const* d_in, const int* in_sizes, int n_in,
                              void* d_out, int out_size, void* d_ws, size_t ws_size,
                              hipStream_t stream) {
    const float* x_seq   = (const float*)d_in[0];
    const int*   ei      = (const int*)d_in[1];
    const float* Wg      = (const float*)d_in[2];
    const float* att_src = (const float*)d_in[3];
    const float* att_dst = (const float*)d_in[4];
    const float* bias_g  = (const float*)d_in[5];
    const float* W_ih    = (const float*)d_in[6];
    const float* W_hh    = (const float*)d_in[7];
    const float* b_ih    = (const float*)d_in[8];
    const float* b_hh    = (const float*)d_in[9];
    const float* W_fc    = (const float*)d_in[10];
    const float* b_fc    = (const float*)d_in[11];
    float* out = (float*)d_out;

    const int N = NN;
    const int E = in_sizes[1] / 2;
    const int* src = ei;
    const int* dst = ei + E;

    // workspace layout
    char* w = (char*)d_ws;
    size_t off = 0;
    auto alloc = [&](size_t bytes) {
        char* p = w + off;
        off = (off + bytes + 255) & ~(size_t)255;
        return p;
    };
    int*   deg     = (int*)alloc((size_t)N * 4);
    int*   row_ptr = (int*)alloc((size_t)(N + 1) * 4);
    int*   cursor  = (int*)alloc((size_t)N * 4);
    int*   col     = (int*)alloc((size_t)(E + N) * 4);
    float* a_s     = (float*)alloc((size_t)N * 4);
    float* a_d     = (float*)alloc((size_t)N * 4);
    unsigned* xpb  = (unsigned*)alloc((size_t)N * 64 * 4);   // bf16 xp [N][128]
    float* spatial = (float*)alloc((size_t)N * HD * 4);
    float* hbuf    = (float*)alloc((size_t)N * HD * 4);
    short* wfrag   = (short*)alloc((size_t)3 * 4 * 8 * 4 * 64 * 8 * 2);  // 393KB

    // h0 = 0
    hipMemsetAsync(hbuf, 0, (size_t)N * HD * 4, stream);

    // CSR build + weight pack (once per launch)
    deg_init_kernel<<<(N + 255) / 256, 256, 0, stream>>>(deg, N);
    deg_count_kernel<<<(E + 255) / 256, 256, 0, stream>>>(dst, deg, E);
    scan_kernel<<<1, 1024, 0, stream>>>(deg, row_ptr, N);
    selfloop_kernel<<<(N + 255) / 256, 256, 0, stream>>>(row_ptr, cursor, col, N);
    scatter_kernel<<<(E + 255) / 256, 256, 0, stream>>>(src, dst, cursor, col, E);
    wpack_kernel<<<(24576 + 255) / 256, 256, 0, stream>>>(W_ih, W_hh, wfrag);

    int node_wave_blocks = (N * 64 + 255) / 256;  // one wave per node
    int gru_blocks = (N + 63) / 64;               // 64-node tiles (R2)

    for (int t = 0; t < SEQ; ++t) {
        const float* xt = x_seq + (size_t)t * N * FIN;
        xp_kernel<<<node_wave_blocks, 256, 0, stream>>>(xt, Wg, att_src, att_dst,
                                                        xpb, a_s, a_d, N);
        gat_kernel<<<node_wave_blocks, 256, 0, stream>>>(row_ptr, col, a_s, a_d,
                                                         (const short*)xpb, bias_g,
                                                         spatial, N);
        gru_mfma_kernel<<<gru_blocks, 256, 0, stream>>>(spatial, hbuf, wfrag,
                                                        b_ih, b_hh, N);
    }
    fc_kernel<<<node_wave_blocks, 256, 0, stream>>>(hbuf, W_fc, b_fc, out, N);
}

// Round 4
// 6299.088 us; speedup vs baseline: 1.0751x; 1.0751x over previous
//
#include <hip/hip_runtime.h>
#include <math.h>

// Problem constants (match reference)
#define NN 50000
#define SEQ 52
#define FIN 16
#define HD 128
#define NEG_SLOPE 0.2f

typedef short bf16x8 __attribute__((ext_vector_type(8)));   // 8 bf16 (4 VGPRs)
typedef float f32x16 __attribute__((ext_vector_type(16)));  // 32x32 MFMA C/D

__device__ __forceinline__ short f2bf(float x) {
    unsigned u = __float_as_uint(x);
    u += 0x7fffu + ((u >> 16) & 1u);   // round-to-nearest-even
    return (short)(u >> 16);
}
__device__ __forceinline__ float b2f(short s) {
    return __uint_as_float(((unsigned)(unsigned short)s) << 16);
}

// ---------------------------------------------------------------------------
// CSR build kernels (run once per launch; graph is static across timesteps)
// ---------------------------------------------------------------------------
__global__ void deg_init_kernel(int* deg, int n) {
    int i = blockIdx.x * blockDim.x + threadIdx.x;
    if (i < n) deg[i] = 1;  // self-loop
}

__global__ void deg_count_kernel(const int* __restrict__ dst, int* deg, int e) {
    int i = blockIdx.x * blockDim.x + threadIdx.x;
    if (i < e) atomicAdd(&deg[dst[i]], 1);
}

__global__ __launch_bounds__(1024) void scan_kernel(const int* __restrict__ deg,
                                                    int* row_ptr, int n) {
    __shared__ int buf[1024];
    __shared__ int carry;
    int tid = threadIdx.x;
    if (tid == 0) carry = 0;
    __syncthreads();
    for (int base = 0; base < n; base += 1024) {
        int i = base + tid;
        int v = (i < n) ? deg[i] : 0;
        buf[tid] = v;
        __syncthreads();
        for (int off = 1; off < 1024; off <<= 1) {
            int t = (tid >= off) ? buf[tid - off] : 0;
            __syncthreads();
            buf[tid] += t;
            __syncthreads();
        }
        if (i < n) row_ptr[i] = carry + buf[tid] - v;  // exclusive
        __syncthreads();
        if (tid == 1023) carry += buf[1023];
        __syncthreads();
    }
    if (tid == 0) row_ptr[n] = carry;
}

__global__ void selfloop_kernel(const int* __restrict__ row_ptr, int* cursor,
                                int* col, int n) {
    int i = blockIdx.x * blockDim.x + threadIdx.x;
    if (i < n) {
        int p = row_ptr[i];
        col[p] = i;          // self-loop first
        cursor[i] = p + 1;
    }
}

__global__ void scatter_kernel(const int* __restrict__ src, const int* __restrict__ dst,
                               int* cursor, int* col, int e) {
    int i = blockIdx.x * blockDim.x + threadIdx.x;
    if (i < e) {
        int p = atomicAdd(&cursor[dst[i]], 1);
        col[p] = src[i];
    }
}

// ---------------------------------------------------------------------------
// Pack W_ih/W_hh into MFMA B-fragment order, split bf16 hi/lo.
// Index: ((((g*4+slab)*8+ks)*4+which)*64+lane)*8 shorts,
//   which: 0=ih_hi 1=ih_lo 2=hh_hi 3=hh_lo
//   col = slab*32 + (lane&31), kcol = ks*16 + (lane>>5)*8
// ---------------------------------------------------------------------------
__global__ void wpack_kernel(const float* __restrict__ Wi, const float* __restrict__ Wh,
                             short* __restrict__ wfrag) {
    int idx = blockIdx.x * blockDim.x + threadIdx.x;
    if (idx >= 3 * 4 * 8 * 4 * 64) return;
    int lane = idx & 63;
    int which = (idx >> 6) & 3;
    int ks = (idx >> 8) & 7;
    int slab = (idx >> 11) & 3;
    int g = idx >> 13;
    int col = slab * 32 + (lane & 31);
    int kcol = ks * 16 + (lane >> 5) * 8;
    const float* Wsrc = (which < 2) ? Wi : Wh;
    const float* row = Wsrc + (size_t)(g * HD + col) * HD + kcol;
    short* dstp = wfrag + (size_t)idx * 8;
    bool lo = (which & 1);
#pragma unroll
    for (int e = 0; e < 8; ++e) {
        float v = row[e];
        short hi = f2bf(v);
        dstp[e] = lo ? f2bf(v - b2f(hi)) : hi;
    }
}

// ---------------------------------------------------------------------------
// Per-timestep kernels
// ---------------------------------------------------------------------------

// xp = x_t @ Wg (stored bf16); a_s = xp.att_src ; a_d = xp.att_dst
__global__ __launch_bounds__(256) void xp_kernel(
    const float* __restrict__ x, const float* __restrict__ Wg,
    const float* __restrict__ att_src, const float* __restrict__ att_dst,
    unsigned* __restrict__ xpb, float* __restrict__ a_s, float* __restrict__ a_d, int n) {
    int wave = (blockIdx.x * blockDim.x + threadIdx.x) >> 6;
    int lane = threadIdx.x & 63;
    if (wave >= n) return;
    const float* xr = x + (size_t)wave * FIN;
    float xv[FIN];
#pragma unroll
    for (int k = 0; k < FIN; ++k) xv[k] = xr[k];
    int c0 = 2 * lane, c1 = 2 * lane + 1;
    float v0 = 0.f, v1 = 0.f;
#pragma unroll
    for (int k = 0; k < FIN; ++k) {
        v0 += xv[k] * Wg[k * HD + c0];
        v1 += xv[k] * Wg[k * HD + c1];
    }
    unsigned p = (unsigned)(unsigned short)f2bf(v0) |
                 ((unsigned)(unsigned short)f2bf(v1) << 16);
    xpb[(size_t)wave * 64 + lane] = p;
    float s = v0 * att_src[c0] + v1 * att_src[c1];
    float d = v0 * att_dst[c0] + v1 * att_dst[c1];
#pragma unroll
    for (int off = 32; off; off >>= 1) {
        s += __shfl_xor(s, off);
        d += __shfl_xor(d, off);
    }
    if (lane == 0) { a_s[wave] = s; a_d[wave] = d; }
}

// ---------------------------------------------------------------------------
// Fused GAT + GRU kernel (R3/R4).
// Block = 256 threads = 4 waves, owns 32 dst nodes (n0..n0+31).
//
// GAT phase: 16-lane group per node (16 groups x 2 nodes each). Per <=16-edge
//   chunk: lane e gathers col/a_s/score in parallel; then each lane streams
//   its 16B feature slice for every edge, 4 rows in flight, (src,wgt)
//   broadcast group-internally via __shfl (exec-uniform within the group:
//   the edge loop bounds are node-uniform, so all 16 lanes of a group are
//   active whenever any is; shfl only sources lanes inside the group).
//   Epilogue: relu+bias, convert to split-bf16, store DIRECTLY into LDS in
//   the MFMA A-frag layout: sSH[(fg>>1)*64 + (fg&1)*32 + nl].
//   -> `spatial` never touches global memory (was 25.6MB write + 25.6MB
//      read per step), and one kernel launch per step disappears.
//
// h staging: global loads ISSUED BEFORE the gat phase, converted/written to
//   LDS after it -> HBM latency hidden under gat compute.
//
// GRU phase: R1-proven core, unchanged (32-node tile, triple-buffered weight
//   prefetch, 4 accumulators: merged r,z; separate i_n,h_n; split-bf16).
// Bonus: on each CU, block k's MFMA-heavy gru overlaps block k+1's
//   VMEM-heavy gat (complementary pipes).
// ---------------------------------------------------------------------------
__global__ __launch_bounds__(256, 2) void gatgru_kernel(
    const int* __restrict__ row_ptr, const int* __restrict__ col,
    const float* __restrict__ a_s, const float* __restrict__ a_d,
    const short* __restrict__ xpb, const float* __restrict__ bias_g,
    float* __restrict__ h, const short* __restrict__ wfrag,
    const float* __restrict__ b_ih, const float* __restrict__ b_hh, int n) {
    __shared__ bf16x8 sSH[512];  // spatial hi (gat output, A-frag layout)
    __shared__ bf16x8 sSL[512];  // spatial lo
    __shared__ bf16x8 sHH[512];  // h hi
    __shared__ bf16x8 sHL[512];  // h lo

    int t = threadIdx.x;
    int lane = t & 63;
    int w = t >> 6;
    int n0 = blockIdx.x * 32;

    // ---- issue h loads early (consumed after gat phase) ----
    float h8[2][8];
#pragma unroll
    for (int q = 0; q < 2; ++q) {
        int ks = w * 2 + q;
        int row = n0 + (lane & 31);
        if (row >= n) row = n - 1;
        int kcol = ks * 16 + (lane >> 5) * 8;
        const float* hp = h + (size_t)row * HD + kcol;
        *(float4*)(h8[q]) = *(const float4*)(hp);
        *(float4*)(h8[q] + 4) = *(const float4*)(hp + 4);
    }

    // ---- GAT phase: 16-lane group per node, 2 nodes per group ----
    int g = t >> 4;          // group 0..15
    int fg = t & 15;         // feature lane: features fg*8..fg*8+7
    int glane = lane & 0x30; // group base lane within wave

#pragma unroll
    for (int nn = 0; nn < 2; ++nn) {
        int nl = g + nn * 16;   // local node 0..31
        int nd = n0 + nl;
        int sidx = (fg >> 1) * 64 + (fg & 1) * 32 + nl;  // A-frag LDS slot
        if (nd < n) {
            int start = row_ptr[nd], end = row_ptr[nd + 1];
            float ad = a_d[nd];
            float acc[8] = {0.f, 0.f, 0.f, 0.f, 0.f, 0.f, 0.f, 0.f};
            float dpart = 0.f;
            for (int base = start; base < end; base += 16) {
                int cnt = end - base;
                if (cnt > 16) cnt = 16;
                // phase 1: lane fg gathers edge base+fg
                int s = 0;
                float wgt = 0.f;
                if (fg < cnt) {
                    s = col[base + fg];
                    float e = a_s[s] + ad;
                    e = (e > 0.f) ? e : NEG_SLOPE * e;
                    wgt = __expf(e);
                }
                dpart += wgt;
                // phase 2: stream rows, 4 in flight, group-internal shfl
                for (int k = 0; k < cnt; k += 4) {
                    int si[4];
                    float wt[4];
#pragma unroll
                    for (int u = 0; u < 4; ++u) {
                        int c = k + u;
                        int cc = (c < cnt) ? c : 0;
                        si[u] = __shfl(s, glane | cc);
                        wt[u] = __shfl(wgt, glane | cc);
                        if (c >= cnt) wt[u] = 0.f;
                    }
                    bf16x8 r[4];
#pragma unroll
                    for (int u = 0; u < 4; ++u)
                        r[u] = *(const bf16x8*)(xpb + (size_t)si[u] * HD + fg * 8);
#pragma unroll
                    for (int u = 0; u < 4; ++u)
#pragma unroll
                        for (int j = 0; j < 8; ++j) acc[j] += wt[u] * b2f(r[u][j]);
                }
            }
            // denom reduce across the 16-lane group
            dpart += __shfl_xor(dpart, 8);
            dpart += __shfl_xor(dpart, 4);
            dpart += __shfl_xor(dpart, 2);
            dpart += __shfl_xor(dpart, 1);
            float inv = __fdividef(1.f, dpart);
            bf16x8 sh, sl;
#pragma unroll
            for (int j = 0; j < 8; ++j) {
                float o = acc[j] * inv + bias_g[fg * 8 + j];
                o = fmaxf(o, 0.f);
                short hi = f2bf(o);
                sh[j] = hi;
                sl[j] = f2bf(o - b2f(hi));
            }
            sSH[sidx] = sh;
            sSL[sidx] = sl;
        } else {
            bf16x8 z;
#pragma unroll
            for (int j = 0; j < 8; ++j) z[j] = 0;
            sSH[sidx] = z;
            sSL[sidx] = z;
        }
    }

    // ---- convert + write h tiles (loads have drained under gat) ----
#pragma unroll
    for (int q = 0; q < 2; ++q) {
        int ks = w * 2 + q;
        bf16x8 hh, hl;
#pragma unroll
        for (int j = 0; j < 8; ++j) {
            short b = f2bf(h8[q][j]);
            hh[j] = b;
            hl[j] = f2bf(h8[q][j] - b2f(b));
        }
        int li = ks * 64 + lane;
        sHH[li] = hh;
        sHL[li] = hl;
    }
    __syncthreads();

    // ---- GRU phase (R1 core) ----
    int j0 = w * 32;
    int cj = lane & 31;       // column within wave's 32-col slab
    int kh = lane >> 5;       // k-half for frags

    f32x16 arz[2], ain, ahn;  // r, z (merged i+h), i_n, h_n
#pragma unroll
    for (int r = 0; r < 16; ++r) {
        arz[0][r] = 0.f; arz[1][r] = 0.f; ain[r] = 0.f; ahn[r] = 0.f;
    }

    // fragment-ordered weight base for this wave: + g*65536 + ks*2048 + which*512
    const short* wb = wfrag + (size_t)w * 16384 + (size_t)lane * 8;

    // weight triple buffer: [buf][g*4 + which]
    bf16x8 wv[3][12];
#pragma unroll
    for (int p = 0; p < 2; ++p) {
#pragma unroll
        for (int gg = 0; gg < 3; ++gg) {
#pragma unroll
            for (int q = 0; q < 4; ++q)
                wv[p][gg * 4 + q] = *(const bf16x8*)(wb + gg * 65536 + p * 2048 + q * 512);
        }
    }

#pragma unroll
    for (int ks = 0; ks < 8; ++ks) {
        int cur = ks % 3;
        if (ks < 6) {
            int nxt = (ks + 2) % 3;
#pragma unroll
            for (int gg = 0; gg < 3; ++gg) {
#pragma unroll
                for (int q = 0; q < 4; ++q)
                    wv[nxt][gg * 4 + q] =
                        *(const bf16x8*)(wb + gg * 65536 + (ks + 2) * 2048 + q * 512);
            }
        }
        int li = ks * 64 + lane;
        bf16x8 aSH = sSH[li];
        bf16x8 aSL = sSL[li];
        bf16x8 aHH = sHH[li];
        bf16x8 aHL = sHL[li];
        // r and z gates: both GEMMs into one accumulator
#pragma unroll
        for (int gg = 0; gg < 2; ++gg) {
            bf16x8 wih = wv[cur][gg * 4 + 0];
            bf16x8 wil = wv[cur][gg * 4 + 1];
            bf16x8 whh = wv[cur][gg * 4 + 2];
            bf16x8 whl = wv[cur][gg * 4 + 3];
            arz[gg] = __builtin_amdgcn_mfma_f32_32x32x16_bf16(aSH, wih, arz[gg], 0, 0, 0);
            arz[gg] = __builtin_amdgcn_mfma_f32_32x32x16_bf16(aHH, whh, arz[gg], 0, 0, 0);
            arz[gg] = __builtin_amdgcn_mfma_f32_32x32x16_bf16(aSL, wih, arz[gg], 0, 0, 0);
            arz[gg] = __builtin_amdgcn_mfma_f32_32x32x16_bf16(aHL, whh, arz[gg], 0, 0, 0);
            arz[gg] = __builtin_amdgcn_mfma_f32_32x32x16_bf16(aSH, wil, arz[gg], 0, 0, 0);
            arz[gg] = __builtin_amdgcn_mfma_f32_32x32x16_bf16(aHH, whl, arz[gg], 0, 0, 0);
        }
        // n gate: separate accs (r multiplies h_n before tanh)
        {
            bf16x8 wih = wv[cur][8];
            bf16x8 wil = wv[cur][9];
            bf16x8 whh = wv[cur][10];
            bf16x8 whl = wv[cur][11];
            ain = __builtin_amdgcn_mfma_f32_32x32x16_bf16(aSH, wih, ain, 0, 0, 0);
            ahn = __builtin_amdgcn_mfma_f32_32x32x16_bf16(aHH, whh, ahn, 0, 0, 0);
            ain = __builtin_amdgcn_mfma_f32_32x32x16_bf16(aSL, wih, ain, 0, 0, 0);
            ahn = __builtin_amdgcn_mfma_f32_32x32x16_bf16(aHL, whh, ahn, 0, 0, 0);
            ain = __builtin_amdgcn_mfma_f32_32x32x16_bf16(aSH, wil, ain, 0, 0, 0);
            ahn = __builtin_amdgcn_mfma_f32_32x32x16_bf16(aHH, whl, ahn, 0, 0, 0);
        }
    }

    // ---- wave-local GRU elementwise + h write ----
    int j = j0 + cj;
    float brz0 = b_ih[j] + b_hh[j];
    float brz1 = b_ih[HD + j] + b_hh[HD + j];
    float bin_ = b_ih[2 * HD + j];
    float bhn = b_hh[2 * HD + j];
    const short* hhs = (const short*)sHH;
    const short* hls = (const short*)sHL;
    int ksj = j >> 4, halfj = (j >> 3) & 1, ej = j & 7;

#pragma unroll
    for (int r = 0; r < 16; ++r) {
        int nl = (r & 3) + 8 * (r >> 2) + 4 * kh;  // C/D row mapping (m74/m101)
        int node = n0 + nl;
        if (node < n) {
            float rr = __fdividef(1.f, 1.f + __expf(-(arz[0][r] + brz0)));
            float zz = __fdividef(1.f, 1.f + __expf(-(arz[1][r] + brz1)));
            float u = ain[r] + bin_ + rr * (ahn[r] + bhn);
            float ex = __expf(2.f * u);
            float nn2 = 1.f - __fdividef(2.f, ex + 1.f);  // tanh(u)
            int li = (ksj * 64 + nl + 32 * halfj) * 8 + ej;
            float hold = b2f(hhs[li]) + b2f(hls[li]);
            h[(size_t)node * HD + j] = (1.f - zz) * nn2 + zz * hold;
        }
    }
}

// out[n] = h[n] . W_fc + b_fc   (one wave per node)
__global__ __launch_bounds__(256) void fc_kernel(
    const float* __restrict__ h, const float* __restrict__ W_fc,
    const float* __restrict__ b_fc, float* __restrict__ out, int n) {
    int wave = (blockIdx.x * blockDim.x + threadIdx.x) >> 6;
    int lane = threadIdx.x & 63;
    if (wave >= n) return;
    float v = h[(size_t)wave * HD + lane] * W_fc[lane] +
              h[(size_t)wave * HD + lane + 64] * W_fc[lane + 64];
#pragma unroll
    for (int off = 32; off; off >>= 1) v += __shfl_xor(v, off);
    if (lane == 0) out[wave] = v + b_fc[0];
}

// ---------------------------------------------------------------------------
extern "C" void kernel_launch(void* const* d_in, const int* in_sizes, int n_in,
                              void* d_out, int out_size, void* d_ws, size_t ws_size,
                              hipStream_t stream) {
    const float* x_seq   = (const float*)d_in[0];
    const int*   ei      = (const int*)d_in[1];
    const float* Wg      = (const float*)d_in[2];
    const float* att_src = (const float*)d_in[3];
    const float* att_dst = (const float*)d_in[4];
    const float* bias_g  = (const float*)d_in[5];
    const float* W_ih    = (const float*)d_in[6];
    const float* W_hh    = (const float*)d_in[7];
    const float* b_ih    = (const float*)d_in[8];
    const float* b_hh    = (const float*)d_in[9];
    const float* W_fc    = (const float*)d_in[10];
    const float* b_fc    = (const float*)d_in[11];
    float* out = (float*)d_out;

    const int N = NN;
    const int E = in_sizes[1] / 2;
    const int* src = ei;
    const int* dst = ei + E;

    // workspace layout
    char* w = (char*)d_ws;
    size_t off = 0;
    auto alloc = [&](size_t bytes) {
        char* p = w + off;
        off = (off + bytes + 255) & ~(size_t)255;
        return p;
    };
    int*   deg     = (int*)alloc((size_t)N * 4);
    int*   row_ptr = (int*)alloc((size_t)(N + 1) * 4);
    int*   cursor  = (int*)alloc((size_t)N * 4);
    int*   col     = (int*)alloc((size_t)(E + N) * 4);
    float* a_s     = (float*)alloc((size_t)N * 4);
    float* a_d     = (float*)alloc((size_t)N * 4);
    unsigned* xpb  = (unsigned*)alloc((size_t)N * 64 * 4);   // bf16 xp [N][128]
    float* hbuf    = (float*)alloc((size_t)N * HD * 4);
    short* wfrag   = (short*)alloc((size_t)3 * 4 * 8 * 4 * 64 * 8 * 2);  // 393KB

    // h0 = 0
    hipMemsetAsync(hbuf, 0, (size_t)N * HD * 4, stream);

    // CSR build + weight pack (once per launch)
    deg_init_kernel<<<(N + 255) / 256, 256, 0, stream>>>(deg, N);
    deg_count_kernel<<<(E + 255) / 256, 256, 0, stream>>>(dst, deg, E);
    scan_kernel<<<1, 1024, 0, stream>>>(deg, row_ptr, N);
    selfloop_kernel<<<(N + 255) / 256, 256, 0, stream>>>(row_ptr, cursor, col, N);
    scatter_kernel<<<(E + 255) / 256, 256, 0, stream>>>(src, dst, cursor, col, E);
    wpack_kernel<<<(24576 + 255) / 256, 256, 0, stream>>>(W_ih, W_hh, wfrag);

    int node_wave_blocks = (N * 64 + 255) / 256;  // one wave per node
    int fused_blocks = (N + 31) / 32;             // 32-node fused tiles

    for (int t = 0; t < SEQ; ++t) {
        const float* xt = x_seq + (size_t)t * N * FIN;
        xp_kernel<<<node_wave_blocks, 256, 0, stream>>>(xt, Wg, att_src, att_dst,
                                                        xpb, a_s, a_d, N);
        gatgru_kernel<<<fused_blocks, 256, 0, stream>>>(row_ptr, col, a_s, a_d,
                                                        (const short*)xpb, bias_g,
                                                        hbuf, wfrag, b_ih, b_hh, N);
    }
    fc_kernel<<<node_wave_blocks, 256, 0, stream>>>(hbuf, W_fc, b_fc, out, N);
}